// Round 3
// baseline (3734.591 us; speedup 1.0000x reference)
//
#include <hip/hip_runtime.h>

typedef unsigned short ushort_t;
typedef __attribute__((ext_vector_type(8))) short short8;
typedef __attribute__((ext_vector_type(4))) short shortx4;
typedef __attribute__((ext_vector_type(4))) float floatx4;

#define D_    768
#define SMAX  237
#define S0_   197
#define RPAD  7680
#define NHEAD 12
#define BATCH 32

// Token-major activations: row(s,b) = s*32 + b. Layers >=5 use M=6400.

__device__ __forceinline__ ushort_t f2bf(float f) {
  union { float f; unsigned u; } v; v.f = f;
  unsigned r = v.u + 0x7FFFu + ((v.u >> 16) & 1u);   // RNE
  return (ushort_t)(r >> 16);
}
__device__ __forceinline__ float bf2f(ushort_t u) {
  union { unsigned u; float f; } v; v.u = ((unsigned)u) << 16; return v.f;
}
__device__ __forceinline__ void async16(const void* g, void* l) {
  __builtin_amdgcn_global_load_lds((const __attribute__((address_space(1))) void*)g,
                                   (__attribute__((address_space(3))) void*)l, 16, 0, 0);
}

// ---------------------------------------------------------------- patchify
__global__ __launch_bounds__(256) void patchify_kernel(
    const float* __restrict__ in, ushort_t* __restrict__ Xp) {
  int rowid = blockIdx.x;                 // 0..6271 = b*196+p
  int b = rowid / 196, p = rowid - b * 196;
  int py = p / 14, px = p - py * 14;
  int tid = threadIdx.x;
#pragma unroll
  for (int t = 0; t < 3; ++t) {
    int k = tid + t * 256;
    int c = k >> 8, rem = k & 255, i = rem >> 4, j = rem & 15;
    float v = in[(((size_t)b * 3 + c) * 224 + py * 16 + i) * 224 + px * 16 + j];
    Xp[(size_t)rowid * 768 + k] = f2bf(v);
  }
}

// ---------------------------------------------------------------- small fills
__global__ void cvt_bf16_kernel(const float* __restrict__ src, ushort_t* __restrict__ dst, int n) {
  int i = blockIdx.x * 256 + threadIdx.x;
  if (i < n) dst[i] = f2bf(src[i]);
}

__global__ void cls_fill_kernel(const float* __restrict__ cls, const float* __restrict__ pos,
                                float* __restrict__ X) {
  int b = blockIdx.x, d = threadIdx.x;    // row(0,b) = b
  X[(size_t)b * 768 + d] = cls[d] + pos[d];
}

__global__ void prompt_fill_kernel(const float* __restrict__ prompts, const float* __restrict__ pos,
                                   const int* __restrict__ eid, float* __restrict__ X, int layer) {
  int id = blockIdx.x;
  int b = id / 40, p = id - b * 40;
  int e = eid[b];
  float v = prompts[(((size_t)layer * 10 + e) * 40 + p) * 768 + threadIdx.x] + pos[threadIdx.x];
  X[((size_t)(197 + p) * 32 + b) * 768 + threadIdx.x] = v;
}

// ---------------------------------------------------------------- weight transpose+cast
// 64x64 tiles: 1728 blocks per layer; l = l0 + id/1728; dst slot = l*slot_mul.
// qkv 432 | proj 144 | fc1 576 | fc2 576
__global__ __launch_bounds__(256) void transpose_wts_kernel(
    const float* __restrict__ qkvw, const float* __restrict__ projw,
    const float* __restrict__ fc1w, const float* __restrict__ fc2w,
    ushort_t* __restrict__ wq, ushort_t* __restrict__ wp,
    ushort_t* __restrict__ w1, ushort_t* __restrict__ w2,
    int l0, int slot_mul) {
  int id = blockIdx.x;
  int l = l0 + id / 1728;
  int t = id % 1728;
  size_t s = (size_t)(l * slot_mul);
  const float* src; ushort_t* dst; int K, N;
  if (t < 432)       { src = qkvw + (size_t)l * 768 * 2304; dst = wq + s * 2304 * 768; K = 768;  N = 2304; }
  else if (t < 576)  { src = projw + (size_t)l * 768 * 768;  dst = wp + s * 768 * 768;  K = 768;  N = 768;  t -= 432; }
  else if (t < 1152) { src = fc1w + (size_t)l * 768 * 3072;  dst = w1 + s * 768 * 3072; K = 768;  N = 3072; t -= 576; }
  else               { src = fc2w + (size_t)l * 3072 * 768;  dst = w2 + s * 3072 * 768; K = 3072; N = 768;  t -= 1152; }
  int ntn = N >> 6;
  int k0 = (t / ntn) * 64, n0 = (t % ntn) * 64;
  __shared__ float tile[64][65];
  int tid = threadIdx.x;
#pragma unroll
  for (int q = 0; q < 4; ++q) {
    int slot = q * 256 + tid;           // 1024 slots = 64 rows x 16 float4
    int r = slot >> 4, c4 = (slot & 15) * 4;
    floatx4 v = *(const floatx4*)&src[(size_t)(k0 + r) * N + n0 + c4];
    tile[r][c4] = v[0]; tile[r][c4 + 1] = v[1]; tile[r][c4 + 2] = v[2]; tile[r][c4 + 3] = v[3];
  }
  __syncthreads();
#pragma unroll
  for (int q = 0; q < 2; ++q) {
    int slot = q * 256 + tid;           // 512 slots = 64 n-rows x 8 k-chunks
    int n = slot >> 3, kc = (slot & 7) * 8;
    short8 o;
#pragma unroll
    for (int e = 0; e < 8; ++e) o[e] = (short)f2bf(tile[kc + e][n]);
    *(short8*)&dst[(size_t)(n0 + n) * K + k0 + kc] = o;
  }
}

// ---------------------------------------------------------------- layernorm
// one row per wave, 4 rows per block
__global__ __launch_bounds__(256) void ln_kernel(
    const float* __restrict__ X, const float* __restrict__ s, const float* __restrict__ bt,
    ushort_t* __restrict__ H) {
  int row = blockIdx.x * 4 + (threadIdx.x >> 6);
  int lane = threadIdx.x & 63;
  const float* xr = X + (size_t)row * 768;
  floatx4 v0 = *(const floatx4*)&xr[lane * 4];
  floatx4 v1 = *(const floatx4*)&xr[256 + lane * 4];
  floatx4 v2 = *(const floatx4*)&xr[512 + lane * 4];
  float sum = 0.f, sq = 0.f;
#pragma unroll
  for (int e = 0; e < 4; ++e) {
    sum += v0[e] + v1[e] + v2[e];
    sq  += v0[e] * v0[e] + v1[e] * v1[e] + v2[e] * v2[e];
  }
#pragma unroll
  for (int m = 1; m <= 32; m <<= 1) {
    sum += __shfl_xor(sum, m, 64);
    sq  += __shfl_xor(sq,  m, 64);
  }
  float mean = sum * (1.f / 768.f);
  float var  = sq * (1.f / 768.f) - mean * mean;
  float rs = rsqrtf(var + 1e-6f);
  ushort_t* hr = H + (size_t)row * 768;
#pragma unroll
  for (int w = 0; w < 3; ++w) {
    const floatx4 v = (w == 0) ? v0 : (w == 1) ? v1 : v2;
    shortx4 o;
#pragma unroll
    for (int e = 0; e < 4; ++e) {
      int d = w * 256 + lane * 4 + e;
      o[e] = (short)f2bf((v[e] - mean) * rs * s[d] + bt[d]);
    }
    *(shortx4*)&hr[w * 256 + lane * 4] = o;
  }
}

// ---------------------------------------------------------------- MFMA GEMM epilogues
enum { EPI_BF16 = 0, EPI_GELU = 1, EPI_RESID = 2, EPI_PATCH = 3 };

// Coalesced epilogue for one 16-row x 64-col chunk staged in LDS (stride 66).
// Lane l handles row (l>>2), 16 consecutive cols at (l&3)*16.
template <int EPI>
__device__ __forceinline__ void epi_chunk(const float* ep, int lane,
                                          int row_base, int col_base,
                                          const float* bias, float* XO, ushort_t* O,
                                          const float* pos, int N) {
  int lr = lane >> 2, cb = (lane & 3) * 16;
  int row = row_base + lr;
  int col = col_base + cb;
  const float* src = ep + lr * 66 + cb;
  if (EPI == EPI_BF16 || EPI == EPI_GELU) {
#pragma unroll
    for (int h = 0; h < 2; ++h) {        // two 8-col halves -> 16B stores
      short8 o;
#pragma unroll
      for (int q = 0; q < 2; ++q) {
        floatx4 v = *(const floatx4*)&src[h * 8 + q * 4];
        floatx4 bb = *(const floatx4*)&bias[col + h * 8 + q * 4];
#pragma unroll
        for (int e = 0; e < 4; ++e) {
          float x = v[e] + bb[e];
          if (EPI == EPI_GELU) x = 0.5f * x * (1.0f + erff(x * 0.70710678118f));
          o[q * 4 + e] = (short)f2bf(x);
        }
      }
      *(short8*)&O[(size_t)row * N + col + h * 8] = o;
    }
  } else if (EPI == EPI_RESID) {
#pragma unroll
    for (int q = 0; q < 4; ++q) {
      floatx4 v = *(const floatx4*)&src[q * 4];
      floatx4 bb = *(const floatx4*)&bias[col + q * 4];
      float* dst = &XO[(size_t)row * 768 + col + q * 4];
      floatx4 x = *(const floatx4*)dst;
#pragma unroll
      for (int e = 0; e < 4; ++e) x[e] += v[e] + bb[e];
      *(floatx4*)dst = x;
    }
  } else {  // EPI_PATCH: row = b*196+p -> out row (1+p)*32+b
    int b = row / 196, p = row - b * 196;
    size_t orow = (size_t)(1 + p) * 32 + b;
#pragma unroll
    for (int q = 0; q < 4; ++q) {
      floatx4 v = *(const floatx4*)&src[q * 4];
      floatx4 bb = *(const floatx4*)&bias[col + q * 4];
      floatx4 pp = *(const floatx4*)&pos[(size_t)(1 + p) * 768 + col + q * 4];
      floatx4 x;
#pragma unroll
      for (int e = 0; e < 4; ++e) x[e] = v[e] + bb[e] + pp[e];
      *(floatx4*)&XO[orow * 768 + col + q * 4] = x;
    }
  }
}

// 128x128 tile, BK=64 (qkv, fc1, proj, fc2)
template <int EPI>
__global__ __launch_bounds__(256) void gemm_kernel(
    const ushort_t* __restrict__ A, int lda,
    const ushort_t* __restrict__ BT,
    const float* __restrict__ bias,
    float* __restrict__ XO, ushort_t* __restrict__ O,
    const float* __restrict__ pos,
    int N, int K) {
  __shared__ ushort_t As[128 * 64];
  __shared__ ushort_t Bs[128 * 64];
  int m0 = blockIdx.y * 128, n0 = blockIdx.x * 128;
  int tid = threadIdx.x, lane = tid & 63, wv = tid >> 6;
  int wm = (wv >> 1) * 64, wn = (wv & 1) * 64;
  int fr = lane & 15, kg = lane >> 4;
  int sw = (fr >> 1) & 7;

  floatx4 acc[4][4];
#pragma unroll
  for (int i = 0; i < 4; ++i)
#pragma unroll
    for (int j = 0; j < 4; ++j) acc[i][j] = (floatx4){0.f, 0.f, 0.f, 0.f};

  for (int k0 = 0; k0 < K; k0 += 64) {
#pragma unroll
    for (int t = 0; t < 4; ++t) {
      int flat = (wv * 4 + t) * 64 + lane;       // 1024 slots = 128 rows x 8 chunks
      int row = flat >> 3;
      int ch = ((flat & 7) ^ ((row >> 1) & 7)) * 8;
      async16(A + (size_t)(m0 + row) * lda + k0 + ch, &As[(wv * 4 + t) * 512]);
      async16(BT + (size_t)(n0 + row) * K + k0 + ch, &Bs[(wv * 4 + t) * 512]);
    }
    __syncthreads();
#pragma unroll
    for (int kh = 0; kh < 2; ++kh) {
      short8 af[4], bfr[4];
#pragma unroll
      for (int i = 0; i < 4; ++i)
        af[i] = *(const short8*)&As[(wm + i * 16 + fr) * 64 + (((kh * 4 + kg) ^ sw) * 8)];
#pragma unroll
      for (int j = 0; j < 4; ++j)
        bfr[j] = *(const short8*)&Bs[(wn + j * 16 + fr) * 64 + (((kh * 4 + kg) ^ sw) * 8)];
#pragma unroll
      for (int i = 0; i < 4; ++i)
#pragma unroll
        for (int j = 0; j < 4; ++j)
          acc[i][j] = __builtin_amdgcn_mfma_f32_16x16x32_bf16(af[i], bfr[j], acc[i][j], 0, 0, 0);
    }
    __syncthreads();
  }

  // ---- epilogue via LDS: per-wave 16x66 f32 region; coalesced vector stores.
  float* ep = (wv < 2) ? ((float*)As + wv * 1056) : ((float*)Bs + (wv - 2) * 1056);
  int rbase = kg * 4;
#pragma unroll
  for (int i = 0; i < 4; ++i) {
#pragma unroll
    for (int j = 0; j < 4; ++j)
#pragma unroll
      for (int r = 0; r < 4; ++r)
        ep[(rbase + r) * 66 + j * 16 + fr] = acc[i][j][r];
    __builtin_amdgcn_wave_barrier();   // keep per-wave write->read order visible
    epi_chunk<EPI>(ep, lane, m0 + wm + i * 16, n0 + wn, bias, XO, O, pos, N);
  }
}

// 64x128 tile, BK=64 (patch embed GEMM)
template <int EPI>
__global__ __launch_bounds__(256) void gemm64_kernel(
    const ushort_t* __restrict__ A, int lda,
    const ushort_t* __restrict__ BT,
    const float* __restrict__ bias,
    float* __restrict__ XO, ushort_t* __restrict__ O,
    const float* __restrict__ pos,
    int N, int K) {
  __shared__ ushort_t As[64 * 64];
  __shared__ ushort_t Bs[128 * 64];
  int m0 = blockIdx.y * 64, n0 = blockIdx.x * 128;
  int tid = threadIdx.x, lane = tid & 63, wv = tid >> 6;
  int wm = (wv >> 1) * 32, wn = (wv & 1) * 64;   // 2x2 waves over 64x128
  int fr = lane & 15, kg = lane >> 4;
  int sw = (fr >> 1) & 7;

  floatx4 acc[2][4];
#pragma unroll
  for (int i = 0; i < 2; ++i)
#pragma unroll
    for (int j = 0; j < 4; ++j) acc[i][j] = (floatx4){0.f, 0.f, 0.f, 0.f};

  for (int k0 = 0; k0 < K; k0 += 64) {
#pragma unroll
    for (int t = 0; t < 2; ++t) {  // A: 64 rows x 8 chunks = 512 slots
      int flat = (wv * 2 + t) * 64 + lane;
      int row = flat >> 3;
      int ch = ((flat & 7) ^ ((row >> 1) & 7)) * 8;
      async16(A + (size_t)(m0 + row) * lda + k0 + ch, &As[(wv * 2 + t) * 512]);
    }
#pragma unroll
    for (int t = 0; t < 4; ++t) {  // B: 128 rows x 8 chunks = 1024 slots
      int flat = (wv * 4 + t) * 64 + lane;
      int row = flat >> 3;
      int ch = ((flat & 7) ^ ((row >> 1) & 7)) * 8;
      async16(BT + (size_t)(n0 + row) * K + k0 + ch, &Bs[(wv * 4 + t) * 512]);
    }
    __syncthreads();
#pragma unroll
    for (int kh = 0; kh < 2; ++kh) {
      short8 af[2], bfr[4];
#pragma unroll
      for (int i = 0; i < 2; ++i)
        af[i] = *(const short8*)&As[(wm + i * 16 + fr) * 64 + (((kh * 4 + kg) ^ sw) * 8)];
#pragma unroll
      for (int j = 0; j < 4; ++j)
        bfr[j] = *(const short8*)&Bs[(wn + j * 16 + fr) * 64 + (((kh * 4 + kg) ^ sw) * 8)];
#pragma unroll
      for (int i = 0; i < 2; ++i)
#pragma unroll
        for (int j = 0; j < 4; ++j)
          acc[i][j] = __builtin_amdgcn_mfma_f32_16x16x32_bf16(af[i], bfr[j], acc[i][j], 0, 0, 0);
    }
    __syncthreads();
  }

  // ---- epilogue via LDS (per-wave 16x66 region)
  float* ep = (wv == 0) ? (float*)As : ((float*)Bs + (wv - 1) * 1056);
  int rbase = kg * 4;
#pragma unroll
  for (int i = 0; i < 2; ++i) {
#pragma unroll
    for (int j = 0; j < 4; ++j)
#pragma unroll
      for (int r = 0; r < 4; ++r)
        ep[(rbase + r) * 66 + j * 16 + fr] = acc[i][j][r];
    __builtin_amdgcn_wave_barrier();
    epi_chunk<EPI>(ep, lane, m0 + wm + i * 16, n0 + wn, bias, XO, O, pos, N);
  }
}

// ---------------------------------------------------------------- MFMA flash attention
__global__ __launch_bounds__(256) void attn_kernel(ushort_t* __restrict__ qkv, int S) {
  __shared__ ushort_t Kc[64 * 64];
  __shared__ ushort_t Vt[64 * 72];
  __shared__ ushort_t Pb[4][16 * 72];
  int id = blockIdx.x;
  int qc = id & 3, bh = id >> 2;
  int b = bh / NHEAD, h = bh - b * NHEAD;
  int tid = threadIdx.x, lane = tid & 63, wv = tid >> 6;
  int fr = lane & 15, kg = lane >> 4;
  int q0 = qc * 64 + wv * 16;

  int qr = q0 + fr; if (qr > S - 1) qr = S - 1;
  const ushort_t* qp = qkv + ((size_t)qr * 32 + b) * 2304 + h * 64 + kg * 8;
  short8 qf0 = *(const short8*)qp;
  short8 qf1 = *(const short8*)(qp + 32);

  floatx4 oacc[4];
#pragma unroll
  for (int j = 0; j < 4; ++j) oacc[j] = (floatx4){0.f, 0.f, 0.f, 0.f};
  float lsum[4] = {0.f, 0.f, 0.f, 0.f};

  int ksw = kg ^ (fr & 7);
  int kst_g = (lane & 7) ^ ((lane >> 3) & 7);

  for (int c = 0; c < 4; ++c) {
    int key0 = c * 64;
    __syncthreads();
#pragma unroll
    for (int t = 0; t < 2; ++t) {
      int f = (wv * 2 + t) * 64 + lane;
      int kr = key0 + (f >> 3); if (kr > S - 1) kr = S - 1;
      async16(qkv + ((size_t)kr * 32 + b) * 2304 + 768 + h * 64 + kst_g * 8,
              &Kc[(wv * 2 + t) * 512]);
    }
#pragma unroll
    for (int t = 0; t < 2; ++t) {
      int kc = wv * 2 + t;
      int vr = key0 + lane; if (vr > S - 1) vr = S - 1;
      short8 vv = *(const short8*)(qkv + ((size_t)vr * 32 + b) * 2304 + 1536 + h * 64 + kc * 8);
#pragma unroll
      for (int e = 0; e < 8; ++e) Vt[(kc * 8 + e) * 72 + lane] = (ushort_t)vv[e];
    }
    __syncthreads();

    floatx4 sacc[4];
#pragma unroll
    for (int j = 0; j < 4; ++j) sacc[j] = (floatx4){0.f, 0.f, 0.f, 0.f};
#pragma unroll
    for (int j = 0; j < 4; ++j) {
      int krow = j * 16 + fr;
      short8 b0 = *(const short8*)&Kc[krow * 64 + ksw * 8];
      short8 b1 = *(const short8*)&Kc[krow * 64 + (ksw ^ 4) * 8];
      sacc[j] = __builtin_amdgcn_mfma_f32_16x16x32_bf16(qf0, b0, sacc[j], 0, 0, 0);
      sacc[j] = __builtin_amdgcn_mfma_f32_16x16x32_bf16(qf1, b1, sacc[j], 0, 0, 0);
    }

#pragma unroll
    for (int j = 0; j < 4; ++j) {
      int key = key0 + j * 16 + fr;
      bool valid = key < S;
#pragma unroll
      for (int r = 0; r < 4; ++r) {
        float e = valid ? __expf(sacc[j][r] * 0.125f) : 0.f;
        lsum[r] += e;
        Pb[wv][(kg * 4 + r) * 72 + j * 16 + fr] = f2bf(e);
      }
    }
    __syncthreads();

    const ushort_t* pp = &Pb[wv][fr * 72 + kg * 8];
    short8 p0 = *(const short8*)pp;
    short8 p1 = *(const short8*)(pp + 32);
#pragma unroll
    for (int j = 0; j < 4; ++j) {
      const ushort_t* vp = &Vt[(j * 16 + fr) * 72 + kg * 8];
      short8 v0 = *(const short8*)vp;
      short8 v1 = *(const short8*)(vp + 32);
      oacc[j] = __builtin_amdgcn_mfma_f32_16x16x32_bf16(p0, v0, oacc[j], 0, 0, 0);
      oacc[j] = __builtin_amdgcn_mfma_f32_16x16x32_bf16(p1, v1, oacc[j], 0, 0, 0);
    }
  }

#pragma unroll
  for (int r = 0; r < 4; ++r) {
#pragma unroll
    for (int m = 1; m <= 8; m <<= 1) lsum[r] += __shfl_xor(lsum[r], m, 64);
  }
#pragma unroll
  for (int r = 0; r < 4; ++r) {
    int q = q0 + kg * 4 + r;
    if (q < S) {
      float inv = 1.f / lsum[r];
      ushort_t* op = qkv + ((size_t)q * 32 + b) * 2304 + h * 64;
#pragma unroll
      for (int j = 0; j < 4; ++j) op[j * 16 + fr] = f2bf(oacc[j][r] * inv);
    }
  }
}

// ---------------------------------------------------------------- final LN + expert head
__global__ __launch_bounds__(256) void head_kernel(
    const float* __restrict__ X, const float* __restrict__ ns, const float* __restrict__ nb,
    const int* __restrict__ eid, const float* __restrict__ hw, const float* __restrict__ hb,
    float* __restrict__ out) {
  int b = blockIdx.x, tid = threadIdx.x;
  const float* xr = X + (size_t)b * 768;
  float v0 = xr[tid], v1 = xr[tid + 256], v2 = xr[tid + 512];
  float sum = v0 + v1 + v2;
  float sq = v0 * v0 + v1 * v1 + v2 * v2;
#pragma unroll
  for (int off = 32; off; off >>= 1) {
    sum += __shfl_down(sum, off, 64);
    sq  += __shfl_down(sq,  off, 64);
  }
  __shared__ float red[8];
  __shared__ float feat[768];
  int wv = tid >> 6, ln = tid & 63;
  if (ln == 0) { red[wv] = sum; red[4 + wv] = sq; }
  __syncthreads();
  if (tid == 0) {
    red[0] = red[0] + red[1] + red[2] + red[3];
    red[4] = red[4] + red[5] + red[6] + red[7];
  }
  __syncthreads();
  float mean = red[0] * (1.f / 768.f);
  float var  = red[4] * (1.f / 768.f) - mean * mean;
  float rs = rsqrtf(var + 1e-6f);
  feat[tid]       = (v0 - mean) * rs * ns[tid]       + nb[tid];
  feat[tid + 256] = (v1 - mean) * rs * ns[tid + 256] + nb[tid + 256];
  feat[tid + 512] = (v2 - mean) * rs * ns[tid + 512] + nb[tid + 512];
  __syncthreads();
  int e = eid[b];
  if (tid < 100) {
    float a = hb[e * 100 + tid];
    const float* w = hw + (size_t)e * 768 * 100 + tid;
#pragma unroll 4
    for (int d = 0; d < 768; ++d) a += feat[d] * w[(size_t)d * 100];
    out[b * 100 + tid] = a;
  }
}

// ---------------------------------------------------------------- launcher
extern "C" void kernel_launch(void* const* d_in, const int* in_sizes, int n_in,
                              void* d_out, int out_size, void* d_ws, size_t ws_size,
                              hipStream_t stream) {
  const float* inputs     = (const float*)d_in[0];
  const int*   expert_ids = (const int*)d_in[1];
  const float* patch_w    = (const float*)d_in[2];
  const float* patch_b    = (const float*)d_in[3];
  const float* cls_token  = (const float*)d_in[4];
  const float* pos_embed  = (const float*)d_in[5];
  const float* ln1_s      = (const float*)d_in[6];
  const float* ln1_b      = (const float*)d_in[7];
  const float* qkv_w      = (const float*)d_in[8];
  const float* qkv_b      = (const float*)d_in[9];
  const float* proj_w     = (const float*)d_in[10];
  const float* proj_b     = (const float*)d_in[11];
  const float* ln2_s      = (const float*)d_in[12];
  const float* ln2_b      = (const float*)d_in[13];
  const float* fc1_w      = (const float*)d_in[14];
  const float* fc1_b      = (const float*)d_in[15];
  const float* fc2_w      = (const float*)d_in[16];
  const float* fc2_b      = (const float*)d_in[17];
  const float* norm_s     = (const float*)d_in[18];
  const float* norm_b     = (const float*)d_in[19];
  const float* prompts    = (const float*)d_in[20];
  const float* head_w     = (const float*)d_in[21];
  const float* head_b     = (const float*)d_in[22];
  float* out = (float*)d_out;

  // hoist all 12 layers' weight transposes if scratch allows (289 MB)
  const size_t kHoistNeed = 289100000ull;
  bool hoist = ws_size >= kHoistNeed;
  size_t slots = hoist ? 12 : 1;

  char* ws = (char*)d_ws;
  size_t off = 0;
  ushort_t* WTp = (ushort_t*)(ws + off); off += (size_t)768 * 768 * 2;
  ushort_t* WQ  = (ushort_t*)(ws + off); off += slots * 2304 * 768 * 2;
  ushort_t* WP  = (ushort_t*)(ws + off); off += slots * 768 * 768 * 2;
  ushort_t* W1  = (ushort_t*)(ws + off); off += slots * 768 * 3072 * 2;
  ushort_t* W2  = (ushort_t*)(ws + off); off += slots * 3072 * 768 * 2;
  float*    X   = (float*)(ws + off);    off += (size_t)RPAD * 768 * 4;
  ushort_t* H   = (ushort_t*)(ws + off); off += (size_t)RPAD * 768 * 2;
  ushort_t* QKV = (ushort_t*)(ws + off); off += (size_t)RPAD * 2304 * 2;
  ushort_t* MID = (ushort_t*)(ws + off); off += (size_t)RPAD * 3072 * 2;
  ushort_t* XP  = MID;   // patchify scratch aliases MID

  cvt_bf16_kernel<<<(768 * 768 + 255) / 256, 256, 0, stream>>>(patch_w, WTp, 768 * 768);
  patchify_kernel<<<6272, 256, 0, stream>>>(inputs, XP);
  gemm64_kernel<EPI_PATCH><<<dim3(6, 98), 256, 0, stream>>>(
      XP, 768, WTp, patch_b, X, nullptr, pos_embed, 768, 768);
  cls_fill_kernel<<<BATCH, 768, 0, stream>>>(cls_token, pos_embed, X);

  if (hoist)
    transpose_wts_kernel<<<1728 * 12, 256, 0, stream>>>(
        qkv_w, proj_w, fc1_w, fc2_w, WQ, WP, W1, W2, 0, 1);

  for (int i = 0; i < 12; ++i) {
    int S = (i < 5) ? SMAX : S0_;
    int MT = (i < 5) ? 60 : 50;          // m-tiles of 128 (M = 7680 / 6400)
    if (i < 5)
      prompt_fill_kernel<<<BATCH * 40, 768, 0, stream>>>(prompts, pos_embed, expert_ids, X, i);
    if (!hoist)
      transpose_wts_kernel<<<1728, 256, 0, stream>>>(
          qkv_w, proj_w, fc1_w, fc2_w, WQ, WP, W1, W2, i, 0);
    ushort_t* WQi = WQ + (hoist ? (size_t)i * 2304 * 768 : 0);
    ushort_t* WPi = WP + (hoist ? (size_t)i * 768 * 768 : 0);
    ushort_t* W1i = W1 + (hoist ? (size_t)i * 768 * 3072 : 0);
    ushort_t* W2i = W2 + (hoist ? (size_t)i * 3072 * 768 : 0);

    ln_kernel<<<MT * 32, 256, 0, stream>>>(X, ln1_s + i * 768, ln1_b + i * 768, H);
    gemm_kernel<EPI_BF16><<<dim3(18, MT), 256, 0, stream>>>(
        H, 768, WQi, qkv_b + i * 2304, nullptr, QKV, nullptr, 2304, 768);
    attn_kernel<<<BATCH * NHEAD * 4, 256, 0, stream>>>(QKV, S);
    gemm_kernel<EPI_RESID><<<dim3(6, MT), 256, 0, stream>>>(
        QKV, 2304, WPi, proj_b + i * 768, X, nullptr, nullptr, 768, 768);
    ln_kernel<<<MT * 32, 256, 0, stream>>>(X, ln2_s + i * 768, ln2_b + i * 768, H);
    gemm_kernel<EPI_GELU><<<dim3(24, MT), 256, 0, stream>>>(
        H, 768, W1i, fc1_b + i * 3072, nullptr, MID, nullptr, 3072, 768);
    gemm_kernel<EPI_RESID><<<dim3(6, MT), 256, 0, stream>>>(
        MID, 3072, W2i, fc2_b + i * 768, X, nullptr, nullptr, 768, 3072);
  }

  head_kernel<<<BATCH, 256, 0, stream>>>(X, norm_s, norm_b, expert_ids, head_w, head_b, out);
}

// Round 4
// 3140.817 us; speedup vs baseline: 1.1891x; 1.1891x over previous
//
#include <hip/hip_runtime.h>

typedef unsigned short ushort_t;
typedef __attribute__((ext_vector_type(8))) short short8;
typedef __attribute__((ext_vector_type(4))) short shortx4;
typedef __attribute__((ext_vector_type(4))) float floatx4;
typedef __attribute__((ext_vector_type(16))) float floatx16;

#define D_    768
#define SMAX  237
#define S0_   197
#define RPAD  7680
#define NHEAD 12
#define BATCH 32

// Token-major activations: row(s,b) = s*32 + b. Layers >=5 use M=6400.

__device__ __forceinline__ ushort_t f2bf(float f) {
  union { float f; unsigned u; } v; v.f = f;
  unsigned r = v.u + 0x7FFFu + ((v.u >> 16) & 1u);   // RNE
  return (ushort_t)(r >> 16);
}
__device__ __forceinline__ float bf2f(ushort_t u) {
  union { unsigned u; float f; } v; v.u = ((unsigned)u) << 16; return v.f;
}
__device__ __forceinline__ void async16(const void* g, void* l) {
  __builtin_amdgcn_global_load_lds((const __attribute__((address_space(1))) void*)g,
                                   (__attribute__((address_space(3))) void*)l, 16, 0, 0);
}

// ---------------------------------------------------------------- patchify
__global__ __launch_bounds__(256) void patchify_kernel(
    const float* __restrict__ in, ushort_t* __restrict__ Xp) {
  int rowid = blockIdx.x;                 // 0..6271 = b*196+p
  int b = rowid / 196, p = rowid - b * 196;
  int py = p / 14, px = p - py * 14;
  int tid = threadIdx.x;
#pragma unroll
  for (int t = 0; t < 3; ++t) {
    int k = tid + t * 256;
    int c = k >> 8, rem = k & 255, i = rem >> 4, j = rem & 15;
    float v = in[(((size_t)b * 3 + c) * 224 + py * 16 + i) * 224 + px * 16 + j];
    Xp[(size_t)rowid * 768 + k] = f2bf(v);
  }
}

// ---------------------------------------------------------------- small fills
__global__ void cvt_bf16_kernel(const float* __restrict__ src, ushort_t* __restrict__ dst, int n) {
  int i = blockIdx.x * 256 + threadIdx.x;
  if (i < n) dst[i] = f2bf(src[i]);
}

__global__ void cls_fill_kernel(const float* __restrict__ cls, const float* __restrict__ pos,
                                float* __restrict__ X) {
  int b = blockIdx.x, d = threadIdx.x;    // row(0,b) = b
  X[(size_t)b * 768 + d] = cls[d] + pos[d];
}

__global__ void prompt_fill_kernel(const float* __restrict__ prompts, const float* __restrict__ pos,
                                   const int* __restrict__ eid, float* __restrict__ X, int layer) {
  int id = blockIdx.x;
  int b = id / 40, p = id - b * 40;
  int e = eid[b];
  float v = prompts[(((size_t)layer * 10 + e) * 40 + p) * 768 + threadIdx.x] + pos[threadIdx.x];
  X[((size_t)(197 + p) * 32 + b) * 768 + threadIdx.x] = v;
}

// ---------------------------------------------------------------- weight transpose+cast
// 64x64 tiles: 1728 blocks per layer; l = l0 + id/1728; dst slot = l*slot_mul.
// qkv 432 | proj 144 | fc1 576 | fc2 576
__global__ __launch_bounds__(256) void transpose_wts_kernel(
    const float* __restrict__ qkvw, const float* __restrict__ projw,
    const float* __restrict__ fc1w, const float* __restrict__ fc2w,
    ushort_t* __restrict__ wq, ushort_t* __restrict__ wp,
    ushort_t* __restrict__ w1, ushort_t* __restrict__ w2,
    int l0, int slot_mul) {
  int id = blockIdx.x;
  int l = l0 + id / 1728;
  int t = id % 1728;
  size_t s = (size_t)(l * slot_mul);
  const float* src; ushort_t* dst; int K, N;
  if (t < 432)       { src = qkvw + (size_t)l * 768 * 2304; dst = wq + s * 2304 * 768; K = 768;  N = 2304; }
  else if (t < 576)  { src = projw + (size_t)l * 768 * 768;  dst = wp + s * 768 * 768;  K = 768;  N = 768;  t -= 432; }
  else if (t < 1152) { src = fc1w + (size_t)l * 768 * 3072;  dst = w1 + s * 768 * 3072; K = 768;  N = 3072; t -= 576; }
  else               { src = fc2w + (size_t)l * 3072 * 768;  dst = w2 + s * 3072 * 768; K = 3072; N = 768;  t -= 1152; }
  int ntn = N >> 6;
  int k0 = (t / ntn) * 64, n0 = (t % ntn) * 64;
  __shared__ float tile[64][65];
  int tid = threadIdx.x;
#pragma unroll
  for (int q = 0; q < 4; ++q) {
    int slot = q * 256 + tid;           // 1024 slots = 64 rows x 16 float4
    int r = slot >> 4, c4 = (slot & 15) * 4;
    floatx4 v = *(const floatx4*)&src[(size_t)(k0 + r) * N + n0 + c4];
    tile[r][c4] = v[0]; tile[r][c4 + 1] = v[1]; tile[r][c4 + 2] = v[2]; tile[r][c4 + 3] = v[3];
  }
  __syncthreads();
#pragma unroll
  for (int q = 0; q < 2; ++q) {
    int slot = q * 256 + tid;           // 512 slots = 64 n-rows x 8 k-chunks
    int n = slot >> 3, kc = (slot & 7) * 8;
    short8 o;
#pragma unroll
    for (int e = 0; e < 8; ++e) o[e] = (short)f2bf(tile[kc + e][n]);
    *(short8*)&dst[(size_t)(n0 + n) * K + k0 + kc] = o;
  }
}

// ---------------------------------------------------------------- layernorm
// one row per wave, 4 rows per block
__global__ __launch_bounds__(256) void ln_kernel(
    const float* __restrict__ X, const float* __restrict__ s, const float* __restrict__ bt,
    ushort_t* __restrict__ H) {
  int row = blockIdx.x * 4 + (threadIdx.x >> 6);
  int lane = threadIdx.x & 63;
  const float* xr = X + (size_t)row * 768;
  floatx4 v0 = *(const floatx4*)&xr[lane * 4];
  floatx4 v1 = *(const floatx4*)&xr[256 + lane * 4];
  floatx4 v2 = *(const floatx4*)&xr[512 + lane * 4];
  float sum = 0.f, sq = 0.f;
#pragma unroll
  for (int e = 0; e < 4; ++e) {
    sum += v0[e] + v1[e] + v2[e];
    sq  += v0[e] * v0[e] + v1[e] * v1[e] + v2[e] * v2[e];
  }
#pragma unroll
  for (int m = 1; m <= 32; m <<= 1) {
    sum += __shfl_xor(sum, m, 64);
    sq  += __shfl_xor(sq,  m, 64);
  }
  float mean = sum * (1.f / 768.f);
  float var  = sq * (1.f / 768.f) - mean * mean;
  float rs = rsqrtf(var + 1e-6f);
  ushort_t* hr = H + (size_t)row * 768;
#pragma unroll
  for (int w = 0; w < 3; ++w) {
    const floatx4 v = (w == 0) ? v0 : (w == 1) ? v1 : v2;
    shortx4 o;
#pragma unroll
    for (int e = 0; e < 4; ++e) {
      int d = w * 256 + lane * 4 + e;
      o[e] = (short)f2bf((v[e] - mean) * rs * s[d] + bt[d]);
    }
    *(shortx4*)&hr[w * 256 + lane * 4] = o;
  }
}

// ---------------------------------------------------------------- MFMA GEMM epilogues
enum { EPI_BF16 = 0, EPI_GELU = 1, EPI_RESID = 2, EPI_PATCH = 3 };

template <int EPI>
__device__ __forceinline__ void epi_store(float accv, int row, int col,
                                          const float* bias, float* XO, ushort_t* O,
                                          const float* pos, int N) {
  if (EPI == EPI_BF16) {
    O[(size_t)row * N + col] = f2bf(accv + bias[col]);
  } else if (EPI == EPI_GELU) {
    float v = accv + bias[col];
    float g = 0.5f * v * (1.0f + erff(v * 0.70710678118f));
    O[(size_t)row * N + col] = f2bf(g);
  } else if (EPI == EPI_RESID) {
    XO[(size_t)row * 768 + col] += accv + bias[col];
  } else {  // EPI_PATCH: row = b*196+p -> out row (1+p)*32+b
    int b = row / 196, p = row - b * 196;
    size_t orow = (size_t)(1 + p) * 32 + b;
    XO[orow * 768 + col] = accv + bias[col] + pos[(size_t)(1 + p) * 768 + col];
  }
}

// Bijective XCD-chunked remap: hw assigns xcd = linear_id % 8; give each XCD a
// contiguous chunk of tile space so n-blocks sharing an A-panel share an L2.
__device__ __forceinline__ int xcd_remap(int o, int nwg) {
  int q8 = nwg >> 3, r8 = nwg & 7;
  int xcd = o & 7, idx = o >> 3;
  return (xcd < r8 ? xcd * (q8 + 1) : r8 * (q8 + 1) + (xcd - r8) * q8) + idx;
}

// 128x128 tile, BK=64, 32x32x16 MFMA (qkv, fc1, proj, fc2)
template <int EPI>
__global__ __launch_bounds__(256) void gemm_kernel(
    const ushort_t* __restrict__ A, int lda,
    const ushort_t* __restrict__ BT,
    const float* __restrict__ bias,
    float* __restrict__ XO, ushort_t* __restrict__ O,
    const float* __restrict__ pos,
    int N, int K) {
  __shared__ ushort_t As[128 * 64];
  __shared__ ushort_t Bs[128 * 64];
  int nwg = gridDim.x * gridDim.y;
  int wg = xcd_remap(blockIdx.y * gridDim.x + blockIdx.x, nwg);
  int m0 = (wg / gridDim.x) * 128, n0 = (wg % gridDim.x) * 128;
  int tid = threadIdx.x, lane = tid & 63, wv = tid >> 6;
  int wm = (wv >> 1) * 64, wn = (wv & 1) * 64;
  int r31 = lane & 31, hg = lane >> 5;
  int rs7 = (r31 >> 1) & 7;

  floatx16 acc[2][2];
#pragma unroll
  for (int i = 0; i < 2; ++i)
#pragma unroll
    for (int j = 0; j < 2; ++j)
#pragma unroll
      for (int e = 0; e < 16; ++e) acc[i][j][e] = 0.f;

  for (int k0 = 0; k0 < K; k0 += 64) {
#pragma unroll
    for (int t = 0; t < 4; ++t) {
      int flat = (wv * 4 + t) * 64 + lane;       // 1024 slots = 128 rows x 8 chunks
      int row = flat >> 3;
      int ch = ((flat & 7) ^ ((row >> 1) & 7)) * 8;
      async16(A + (size_t)(m0 + row) * lda + k0 + ch, &As[(wv * 4 + t) * 512]);
      async16(BT + (size_t)(n0 + row) * K + k0 + ch, &Bs[(wv * 4 + t) * 512]);
    }
    __syncthreads();
#pragma unroll
    for (int s = 0; s < 4; ++s) {                // 4 k-slices of 16
      int cc = ((s * 2 + hg) ^ rs7) * 8;
      short8 af0 = *(const short8*)&As[(wm + r31) * 64 + cc];
      short8 af1 = *(const short8*)&As[(wm + 32 + r31) * 64 + cc];
      short8 bf0 = *(const short8*)&Bs[(wn + r31) * 64 + cc];
      short8 bf1 = *(const short8*)&Bs[(wn + 32 + r31) * 64 + cc];
      acc[0][0] = __builtin_amdgcn_mfma_f32_32x32x16_bf16(af0, bf0, acc[0][0], 0, 0, 0);
      acc[0][1] = __builtin_amdgcn_mfma_f32_32x32x16_bf16(af0, bf1, acc[0][1], 0, 0, 0);
      acc[1][0] = __builtin_amdgcn_mfma_f32_32x32x16_bf16(af1, bf0, acc[1][0], 0, 0, 0);
      acc[1][1] = __builtin_amdgcn_mfma_f32_32x32x16_bf16(af1, bf1, acc[1][1], 0, 0, 0);
    }
    __syncthreads();
  }

  // C layout (32x32): col = lane&31, row = (g&3) + 8*(g>>2) + 4*(lane>>5)
#pragma unroll
  for (int i = 0; i < 2; ++i)
#pragma unroll
    for (int j = 0; j < 2; ++j)
#pragma unroll
      for (int g = 0; g < 16; ++g) {
        int row = m0 + wm + i * 32 + (g & 3) + 8 * (g >> 2) + 4 * hg;
        int col = n0 + wn + j * 32 + r31;
        epi_store<EPI>(acc[i][j][g], row, col, bias, XO, O, pos, N);
      }
}

// 64x128 tile, BK=64, 32x32x16 MFMA (patch embed GEMM)
template <int EPI>
__global__ __launch_bounds__(256) void gemm64_kernel(
    const ushort_t* __restrict__ A, int lda,
    const ushort_t* __restrict__ BT,
    const float* __restrict__ bias,
    float* __restrict__ XO, ushort_t* __restrict__ O,
    const float* __restrict__ pos,
    int N, int K) {
  __shared__ ushort_t As[64 * 64];
  __shared__ ushort_t Bs[128 * 64];
  int nwg = gridDim.x * gridDim.y;
  int wg = xcd_remap(blockIdx.y * gridDim.x + blockIdx.x, nwg);
  int m0 = (wg / gridDim.x) * 64, n0 = (wg % gridDim.x) * 128;
  int tid = threadIdx.x, lane = tid & 63, wv = tid >> 6;
  int wm = (wv >> 1) * 32, wn = (wv & 1) * 64;   // 2x2 waves over 64x128
  int r31 = lane & 31, hg = lane >> 5;
  int rs7 = (r31 >> 1) & 7;

  floatx16 acc[2];
#pragma unroll
  for (int j = 0; j < 2; ++j)
#pragma unroll
    for (int e = 0; e < 16; ++e) acc[j][e] = 0.f;

  for (int k0 = 0; k0 < K; k0 += 64) {
#pragma unroll
    for (int t = 0; t < 2; ++t) {  // A: 64 rows x 8 chunks = 512 slots
      int flat = (wv * 2 + t) * 64 + lane;
      int row = flat >> 3;
      int ch = ((flat & 7) ^ ((row >> 1) & 7)) * 8;
      async16(A + (size_t)(m0 + row) * lda + k0 + ch, &As[(wv * 2 + t) * 512]);
    }
#pragma unroll
    for (int t = 0; t < 4; ++t) {  // B: 128 rows x 8 chunks = 1024 slots
      int flat = (wv * 4 + t) * 64 + lane;
      int row = flat >> 3;
      int ch = ((flat & 7) ^ ((row >> 1) & 7)) * 8;
      async16(BT + (size_t)(n0 + row) * K + k0 + ch, &Bs[(wv * 4 + t) * 512]);
    }
    __syncthreads();
#pragma unroll
    for (int s = 0; s < 4; ++s) {
      int cc = ((s * 2 + hg) ^ rs7) * 8;
      short8 af  = *(const short8*)&As[(wm + r31) * 64 + cc];
      short8 bf0 = *(const short8*)&Bs[(wn + r31) * 64 + cc];
      short8 bf1 = *(const short8*)&Bs[(wn + 32 + r31) * 64 + cc];
      acc[0] = __builtin_amdgcn_mfma_f32_32x32x16_bf16(af, bf0, acc[0], 0, 0, 0);
      acc[1] = __builtin_amdgcn_mfma_f32_32x32x16_bf16(af, bf1, acc[1], 0, 0, 0);
    }
    __syncthreads();
  }

#pragma unroll
  for (int j = 0; j < 2; ++j)
#pragma unroll
    for (int g = 0; g < 16; ++g) {
      int row = m0 + wm + (g & 3) + 8 * (g >> 2) + 4 * hg;
      int col = n0 + wn + j * 32 + r31;
      epi_store<EPI>(acc[j][g], row, col, bias, XO, O, pos, N);
    }
}

// ---------------------------------------------------------------- MFMA flash attention
__global__ __launch_bounds__(256) void attn_kernel(ushort_t* __restrict__ qkv, int S) {
  __shared__ ushort_t Kc[64 * 64];
  __shared__ ushort_t Vt[64 * 72];
  __shared__ ushort_t Pb[4][16 * 72];
  int id = blockIdx.x;
  int qc = id & 3, bh = id >> 2;
  int b = bh / NHEAD, h = bh - b * NHEAD;
  int tid = threadIdx.x, lane = tid & 63, wv = tid >> 6;
  int fr = lane & 15, kg = lane >> 4;
  int q0 = qc * 64 + wv * 16;

  int qr = q0 + fr; if (qr > S - 1) qr = S - 1;
  const ushort_t* qp = qkv + ((size_t)qr * 32 + b) * 2304 + h * 64 + kg * 8;
  short8 qf0 = *(const short8*)qp;
  short8 qf1 = *(const short8*)(qp + 32);

  floatx4 oacc[4];
#pragma unroll
  for (int j = 0; j < 4; ++j) oacc[j] = (floatx4){0.f, 0.f, 0.f, 0.f};
  float lsum[4] = {0.f, 0.f, 0.f, 0.f};

  int ksw = kg ^ (fr & 7);
  int kst_g = (lane & 7) ^ ((lane >> 3) & 7);

  for (int c = 0; c < 4; ++c) {
    int key0 = c * 64;
    __syncthreads();
#pragma unroll
    for (int t = 0; t < 2; ++t) {
      int f = (wv * 2 + t) * 64 + lane;
      int kr = key0 + (f >> 3); if (kr > S - 1) kr = S - 1;
      async16(qkv + ((size_t)kr * 32 + b) * 2304 + 768 + h * 64 + kst_g * 8,
              &Kc[(wv * 2 + t) * 512]);
    }
#pragma unroll
    for (int t = 0; t < 2; ++t) {
      int kc = wv * 2 + t;
      int vr = key0 + lane; if (vr > S - 1) vr = S - 1;
      short8 vv = *(const short8*)(qkv + ((size_t)vr * 32 + b) * 2304 + 1536 + h * 64 + kc * 8);
#pragma unroll
      for (int e = 0; e < 8; ++e) Vt[(kc * 8 + e) * 72 + lane] = (ushort_t)vv[e];
    }
    __syncthreads();

    floatx4 sacc[4];
#pragma unroll
    for (int j = 0; j < 4; ++j) sacc[j] = (floatx4){0.f, 0.f, 0.f, 0.f};
#pragma unroll
    for (int j = 0; j < 4; ++j) {
      int krow = j * 16 + fr;
      short8 b0 = *(const short8*)&Kc[krow * 64 + ksw * 8];
      short8 b1 = *(const short8*)&Kc[krow * 64 + (ksw ^ 4) * 8];
      sacc[j] = __builtin_amdgcn_mfma_f32_16x16x32_bf16(qf0, b0, sacc[j], 0, 0, 0);
      sacc[j] = __builtin_amdgcn_mfma_f32_16x16x32_bf16(qf1, b1, sacc[j], 0, 0, 0);
    }

#pragma unroll
    for (int j = 0; j < 4; ++j) {
      int key = key0 + j * 16 + fr;
      bool valid = key < S;
#pragma unroll
      for (int r = 0; r < 4; ++r) {
        float e = valid ? __expf(sacc[j][r] * 0.125f) : 0.f;
        lsum[r] += e;
        Pb[wv][(kg * 4 + r) * 72 + j * 16 + fr] = f2bf(e);
      }
    }
    __syncthreads();

    const ushort_t* pp = &Pb[wv][fr * 72 + kg * 8];
    short8 p0 = *(const short8*)pp;
    short8 p1 = *(const short8*)(pp + 32);
#pragma unroll
    for (int j = 0; j < 4; ++j) {
      const ushort_t* vp = &Vt[(j * 16 + fr) * 72 + kg * 8];
      short8 v0 = *(const short8*)vp;
      short8 v1 = *(const short8*)(vp + 32);
      oacc[j] = __builtin_amdgcn_mfma_f32_16x16x32_bf16(p0, v0, oacc[j], 0, 0, 0);
      oacc[j] = __builtin_amdgcn_mfma_f32_16x16x32_bf16(p1, v1, oacc[j], 0, 0, 0);
    }
  }

#pragma unroll
  for (int r = 0; r < 4; ++r) {
#pragma unroll
    for (int m = 1; m <= 8; m <<= 1) lsum[r] += __shfl_xor(lsum[r], m, 64);
  }
#pragma unroll
  for (int r = 0; r < 4; ++r) {
    int q = q0 + kg * 4 + r;
    if (q < S) {
      float inv = 1.f / lsum[r];
      ushort_t* op = qkv + ((size_t)q * 32 + b) * 2304 + h * 64;
#pragma unroll
      for (int j = 0; j < 4; ++j) op[j * 16 + fr] = f2bf(oacc[j][r] * inv);
    }
  }
}

// ---------------------------------------------------------------- final LN + expert head
__global__ __launch_bounds__(256) void head_kernel(
    const float* __restrict__ X, const float* __restrict__ ns, const float* __restrict__ nb,
    const int* __restrict__ eid, const float* __restrict__ hw, const float* __restrict__ hb,
    float* __restrict__ out) {
  int b = blockIdx.x, tid = threadIdx.x;
  const float* xr = X + (size_t)b * 768;
  float v0 = xr[tid], v1 = xr[tid + 256], v2 = xr[tid + 512];
  float sum = v0 + v1 + v2;
  float sq = v0 * v0 + v1 * v1 + v2 * v2;
#pragma unroll
  for (int off = 32; off; off >>= 1) {
    sum += __shfl_down(sum, off, 64);
    sq  += __shfl_down(sq,  off, 64);
  }
  __shared__ float red[8];
  __shared__ float feat[768];
  int wv = tid >> 6, ln = tid & 63;
  if (ln == 0) { red[wv] = sum; red[4 + wv] = sq; }
  __syncthreads();
  if (tid == 0) {
    red[0] = red[0] + red[1] + red[2] + red[3];
    red[4] = red[4] + red[5] + red[6] + red[7];
  }
  __syncthreads();
  float mean = red[0] * (1.f / 768.f);
  float var  = red[4] * (1.f / 768.f) - mean * mean;
  float rs = rsqrtf(var + 1e-6f);
  feat[tid]       = (v0 - mean) * rs * ns[tid]       + nb[tid];
  feat[tid + 256] = (v1 - mean) * rs * ns[tid + 256] + nb[tid + 256];
  feat[tid + 512] = (v2 - mean) * rs * ns[tid + 512] + nb[tid + 512];
  __syncthreads();
  int e = eid[b];
  if (tid < 100) {
    float a = hb[e * 100 + tid];
    const float* w = hw + (size_t)e * 768 * 100 + tid;
#pragma unroll 4
    for (int d = 0; d < 768; ++d) a += feat[d] * w[(size_t)d * 100];
    out[b * 100 + tid] = a;
  }
}

// ---------------------------------------------------------------- launcher
extern "C" void kernel_launch(void* const* d_in, const int* in_sizes, int n_in,
                              void* d_out, int out_size, void* d_ws, size_t ws_size,
                              hipStream_t stream) {
  const float* inputs     = (const float*)d_in[0];
  const int*   expert_ids = (const int*)d_in[1];
  const float* patch_w    = (const float*)d_in[2];
  const float* patch_b    = (const float*)d_in[3];
  const float* cls_token  = (const float*)d_in[4];
  const float* pos_embed  = (const float*)d_in[5];
  const float* ln1_s      = (const float*)d_in[6];
  const float* ln1_b      = (const float*)d_in[7];
  const float* qkv_w      = (const float*)d_in[8];
  const float* qkv_b      = (const float*)d_in[9];
  const float* proj_w     = (const float*)d_in[10];
  const float* proj_b     = (const float*)d_in[11];
  const float* ln2_s      = (const float*)d_in[12];
  const float* ln2_b      = (const float*)d_in[13];
  const float* fc1_w      = (const float*)d_in[14];
  const float* fc1_b      = (const float*)d_in[15];
  const float* fc2_w      = (const float*)d_in[16];
  const float* fc2_b      = (const float*)d_in[17];
  const float* norm_s     = (const float*)d_in[18];
  const float* norm_b     = (const float*)d_in[19];
  const float* prompts    = (const float*)d_in[20];
  const float* head_w     = (const float*)d_in[21];
  const float* head_b     = (const float*)d_in[22];
  float* out = (float*)d_out;

  // hoist all 12 layers' weight transposes if scratch allows (289 MB)
  const size_t kHoistNeed = 289100000ull;
  bool hoist = ws_size >= kHoistNeed;
  size_t slots = hoist ? 12 : 1;

  char* ws = (char*)d_ws;
  size_t off = 0;
  ushort_t* WTp = (ushort_t*)(ws + off); off += (size_t)768 * 768 * 2;
  ushort_t* WQ  = (ushort_t*)(ws + off); off += slots * 2304 * 768 * 2;
  ushort_t* WP  = (ushort_t*)(ws + off); off += slots * 768 * 768 * 2;
  ushort_t* W1  = (ushort_t*)(ws + off); off += slots * 768 * 3072 * 2;
  ushort_t* W2  = (ushort_t*)(ws + off); off += slots * 3072 * 768 * 2;
  float*    X   = (float*)(ws + off);    off += (size_t)RPAD * 768 * 4;
  ushort_t* H   = (ushort_t*)(ws + off); off += (size_t)RPAD * 768 * 2;
  ushort_t* QKV = (ushort_t*)(ws + off); off += (size_t)RPAD * 2304 * 2;
  ushort_t* MID = (ushort_t*)(ws + off); off += (size_t)RPAD * 3072 * 2;
  ushort_t* XP  = MID;   // patchify scratch aliases MID

  cvt_bf16_kernel<<<(768 * 768 + 255) / 256, 256, 0, stream>>>(patch_w, WTp, 768 * 768);
  patchify_kernel<<<6272, 256, 0, stream>>>(inputs, XP);
  gemm64_kernel<EPI_PATCH><<<dim3(6, 98), 256, 0, stream>>>(
      XP, 768, WTp, patch_b, X, nullptr, pos_embed, 768, 768);
  cls_fill_kernel<<<BATCH, 768, 0, stream>>>(cls_token, pos_embed, X);

  if (hoist)
    transpose_wts_kernel<<<1728 * 12, 256, 0, stream>>>(
        qkv_w, proj_w, fc1_w, fc2_w, WQ, WP, W1, W2, 0, 1);

  for (int i = 0; i < 12; ++i) {
    int S = (i < 5) ? SMAX : S0_;
    int MT = (i < 5) ? 60 : 50;          // m-tiles of 128 (M = 7680 / 6400)
    if (i < 5)
      prompt_fill_kernel<<<BATCH * 40, 768, 0, stream>>>(prompts, pos_embed, expert_ids, X, i);
    if (!hoist)
      transpose_wts_kernel<<<1728, 256, 0, stream>>>(
          qkv_w, proj_w, fc1_w, fc2_w, WQ, WP, W1, W2, i, 0);
    ushort_t* WQi = WQ + (hoist ? (size_t)i * 2304 * 768 : 0);
    ushort_t* WPi = WP + (hoist ? (size_t)i * 768 * 768 : 0);
    ushort_t* W1i = W1 + (hoist ? (size_t)i * 768 * 3072 : 0);
    ushort_t* W2i = W2 + (hoist ? (size_t)i * 3072 * 768 : 0);

    ln_kernel<<<MT * 32, 256, 0, stream>>>(X, ln1_s + i * 768, ln1_b + i * 768, H);
    gemm_kernel<EPI_BF16><<<dim3(18, MT), 256, 0, stream>>>(
        H, 768, WQi, qkv_b + i * 2304, nullptr, QKV, nullptr, 2304, 768);
    attn_kernel<<<BATCH * NHEAD * 4, 256, 0, stream>>>(QKV, S);
    gemm_kernel<EPI_RESID><<<dim3(6, MT), 256, 0, stream>>>(
        QKV, 2304, WPi, proj_b + i * 768, X, nullptr, nullptr, 768, 768);
    ln_kernel<<<MT * 32, 256, 0, stream>>>(X, ln2_s + i * 768, ln2_b + i * 768, H);
    gemm_kernel<EPI_GELU><<<dim3(24, MT), 256, 0, stream>>>(
        H, 768, W1i, fc1_b + i * 3072, nullptr, MID, nullptr, 3072, 768);
    gemm_kernel<EPI_RESID><<<dim3(6, MT), 256, 0, stream>>>(
        MID, 3072, W2i, fc2_b + i * 768, X, nullptr, nullptr, 768, 3072);
  }

  head_kernel<<<BATCH, 256, 0, stream>>>(X, norm_s, norm_b, expert_ids, head_w, head_b, out);
}